// Round 3
// baseline (835.834 us; speedup 1.0000x reference)
//
#include <hip/hip_runtime.h>
#include <hip/hip_bf16.h>
#include <math.h>

#define NSTREAM 4
#define DIM     1024
#define BUSW    4096
#define NTOK    8192      // B*L = 4*2048
#define NPADW   320       // W rows: 256 res + 4 pre + 4 post + pad to 4*80
#define NPR     288       // raw_part row stride (cols 0..263 valid)
#define KSPLIT  4
#define KCH     1024      // BUSW / KSPLIT
#define BM      32
#define BK      32
#define OUT0    ((size_t)16 * 2048 * 1024)   // offset of branch_input in d_out

typedef short bf16x8 __attribute__((ext_vector_type(8)));
typedef float f32x4  __attribute__((ext_vector_type(4)));

__device__ __forceinline__ unsigned short f2bf(float f) {
    union { float f; unsigned int u; } x; x.f = f;
    unsigned int r = x.u + 0x7fffu + ((x.u >> 16) & 1u);
    return (unsigned short)(r >> 16);
}
__device__ __forceinline__ unsigned int pack2(float a, float b) {
    return (unsigned int)f2bf(a) | ((unsigned int)f2bf(b) << 16);
}
__device__ __forceinline__ void gld_lds16(const unsigned short* g, unsigned short* l) {
    __builtin_amdgcn_global_load_lds(
        (const __attribute__((address_space(1))) unsigned int*)g,
        (__attribute__((address_space(3))) unsigned int*)l, 16, 0, 0);
}

// ---------------------------------------------------------------------------
// Kernel 1: pack W into per-k-tile LDS-image order.
// Chunk c (8 shorts): ktc = c/1280 (= kc*32+kt), idx = c%1280, n = idx>>2,
// k = ktc*32 + (idx&3)*8 + j.  Value = (gamma[k]+1)*phi[k][n] (0 for n>=264).
// ---------------------------------------------------------------------------
__global__ void prep_w_kernel(const float* __restrict__ gamma,
                              const float* __restrict__ phi_res,
                              const float* __restrict__ phi_pre,
                              const float* __restrict__ phi_post,
                              unsigned short* __restrict__ Wt) {
    int c = blockIdx.x * 256 + threadIdx.x;      // 0 .. 163839
    int ktc = c / 1280;
    int idx = c - ktc * 1280;
    int n = idx >> 2;
    int kb = ktc * 32 + (idx & 3) * 8;
    float v[8];
#pragma unroll
    for (int j = 0; j < 8; j++) {
        int k = kb + j;
        float p = 0.0f;
        if (n < 256)      p = phi_res[k * 256 + n];
        else if (n < 260) p = phi_pre[k * 4 + (n - 256)];
        else if (n < 264) p = phi_post[k * 4 + (n - 260)];
        v[j] = p * (gamma[k] + 1.0f);
    }
    uint4 u;
    u.x = pack2(v[0], v[1]); u.y = pack2(v[2], v[3]);
    u.z = pack2(v[4], v[5]); u.w = pack2(v[6], v[7]);
    ((uint4*)Wt)[c] = u;
}

// ---------------------------------------------------------------------------
// Kernel 2: split-K GEMM raw_part[kc][token][n] (n<264), MFMA 16x16x32 bf16.
// BM=32 tokens, 4 waves each own an 80-col slice (B read once per block).
// B staged via async global_load_lds (16B) from pre-tiled Wt; A via reg pack.
// Grid: 256 x 4 = 1024 blocks (4/CU).
// ---------------------------------------------------------------------------
__launch_bounds__(256, 4)
__global__ void gemm_raw_kernel(const float* __restrict__ residuals,
                                const unsigned short* __restrict__ Wt,
                                float* __restrict__ raw_part) {
    __shared__ unsigned short Alds[BM * BK];       // 2 KB  [row][k]
    __shared__ unsigned short Blds[NPADW * BK];    // 20 KB [n][k]

    const int tid = threadIdx.x;
    const int wid = tid >> 6, lane = tid & 63;
    const int tb = blockIdx.x, kc = blockIdx.y;
    const int row0 = tb * BM;
    const int fr = lane & 15, hf = lane >> 4;

    f32x4 acc[2][5];
#pragma unroll
    for (int i = 0; i < 2; i++)
#pragma unroll
        for (int j = 0; j < 5; j++) acc[i][j] = (f32x4){0.f, 0.f, 0.f, 0.f};

    // A staging: thread -> row = tid>>3, 4 consecutive k at (tid&7)*4
    const int arow = tid >> 3;
    const int akq  = (tid & 7) * 4;
    const int tok  = row0 + arow;
    const int bidx = tok >> 11, lidx = tok & 2047;
    const float* abase = residuals +
        (((size_t)(bidx * 4 + kc) * 2048 + lidx) * 1024 + akq);
    const unsigned short* wt = Wt + (size_t)kc * 32 * 1280 * 8;

    for (int kt = 0; kt < KCH / BK; kt++) {
        // B: async global->LDS, 20 KB = 5 x (256 lanes x 16 B), lane-contiguous
#pragma unroll
        for (int i = 0; i < 5; i++) {
            int idx = i * 256 + tid;
            gld_lds16(wt + ((size_t)kt * 1280 + idx) * 8, &Blds[idx * 8]);
        }
        // A: fp32 -> bf16 pack, 8 B/thread
        float4 f = *(const float4*)(abase + kt * BK);
        uint2 ua; ua.x = pack2(f.x, f.y); ua.y = pack2(f.z, f.w);
        *(uint2*)&Alds[arow * BK + akq] = ua;
        __syncthreads();

        bf16x8 af[2], bf[5];
#pragma unroll
        for (int mt = 0; mt < 2; mt++)
            af[mt] = *(const bf16x8*)&Alds[(mt * 16 + fr) * BK + hf * 8];
#pragma unroll
        for (int nt = 0; nt < 5; nt++)
            bf[nt] = *(const bf16x8*)&Blds[(wid * 80 + nt * 16 + fr) * BK + hf * 8];
#pragma unroll
        for (int mt = 0; mt < 2; mt++)
#pragma unroll
            for (int nt = 0; nt < 5; nt++)
                acc[mt][nt] = __builtin_amdgcn_mfma_f32_16x16x32_bf16(
                    af[mt], bf[nt], acc[mt][nt], 0, 0, 0);
        __syncthreads();
    }

    // epilogue: C/D mapping col=lane&15, row=(lane>>4)*4+reg
#pragma unroll
    for (int mt = 0; mt < 2; mt++)
#pragma unroll
        for (int nt = 0; nt < 5; nt++) {
            int col = wid * 80 + nt * 16 + fr;
            if (col < 264) {
#pragma unroll
                for (int r = 0; r < 4; r++) {
                    int token = row0 + mt * 16 + hf * 4 + r;
                    raw_part[((size_t)kc * NTOK + token) * NPR + col] = acc[mt][nt][r];
                }
            }
        }
}

// ---------------------------------------------------------------------------
// Kernel 3: block-per-token fused tail. 8192 blocks x 256 thr.
// Bus through LDS once; Sinkhorn in-register on wave 0 (no inner barriers);
// Z/S in 17-padded LDS; 3 barriers total; all global access float4.
// ---------------------------------------------------------------------------
__launch_bounds__(256, 4)
__global__ void fused_tail_kernel(const float* __restrict__ residuals,
                                  const float* __restrict__ branch_output,
                                  const float* __restrict__ H_res_logits,
                                  const float* __restrict__ alpha_res_p,
                                  const float* __restrict__ H_pre_logits,
                                  const float* __restrict__ alpha_pre_p,
                                  const float* __restrict__ H_post_logits,
                                  const float* __restrict__ alpha_post_p,
                                  const float* __restrict__ raw_part,
                                  float* __restrict__ out) {
    const int t = blockIdx.x;
    const int b = t >> 11, lt = t & 2047;
    const int tid = threadIdx.x;
    const int wid = tid >> 6, lane = tid & 63;

    __shared__ float busf[4096];     // [stream][1024]
    __shared__ float Zl[16 * 17];    // Z, then S in place
    __shared__ float extra[8];       // pre/post raw sums (x scale)
    __shared__ float hpre[4], hpost[4];
    __shared__ float redbuf[4];

    // ---- load bus -> LDS + sumsq; each thread: offset wid*256+lane*4 of each stream
    const int off = wid * 256 + lane * 4;
    const float* rbase = residuals + ((size_t)b * 4 * 2048 + lt) * 1024 + off;
    float sumsq = 0.f;
#pragma unroll
    for (int s = 0; s < 4; s++) {
        float4 v = *(const float4*)(rbase + (size_t)s * 2048 * 1024);
        *(float4*)&busf[s * 1024 + off] = v;
        sumsq += v.x * v.x + v.y * v.y + v.z * v.z + v.w * v.w;
    }
    // ---- raw col sum (col = tid) over 4 split-K partials
    const float* rp = raw_part + (size_t)t * NPR + tid;
    float rsum = rp[0] + rp[(size_t)NTOK * NPR] + rp[2 * (size_t)NTOK * NPR]
               + rp[3 * (size_t)NTOK * NPR];
    float esum = 0.f;
    if (tid < 8) {
        const float* ep = raw_part + (size_t)t * NPR + 256 + tid;
        esum = ep[0] + ep[(size_t)NTOK * NPR] + ep[2 * (size_t)NTOK * NPR]
             + ep[3 * (size_t)NTOK * NPR];
    }
#pragma unroll
    for (int m = 1; m < 64; m <<= 1) sumsq += __shfl_xor(sumsq, m, 64);
    if (lane == 0) redbuf[wid] = sumsq;
    __syncthreads();                                          // (1)

    const float scale = 64.0f /
        fmaxf(sqrtf(redbuf[0] + redbuf[1] + redbuf[2] + redbuf[3]), 1e-12f);
    const float a_res = alpha_res_p[0];
    Zl[(tid >> 4) * 17 + (tid & 15)] =
        (a_res * scale * rsum + H_res_logits[tid]) * 20.0f;   // /tau
    if (tid < 8) extra[tid] = esum * scale;
    __syncthreads();                                          // (2)

    if (wid == 0) {
        // ---- Sinkhorn fully in wave 0: lane l owns row r=l>>2, cols (l&3)*4+j
        const int r = lane >> 2, c0 = (lane & 3) * 4;
        float Z[4];
#pragma unroll
        for (int j = 0; j < 4; j++) Z[j] = Zl[r * 17 + c0 + j];
        const float lm = -2.772588722239781f;  // -log(16)
        float vv[4] = {0.f, 0.f, 0.f, 0.f};
        float u = 0.f;
#pragma unroll
        for (int it = 0; it < 10; it++) {
            float m0 = fmaxf(fmaxf(Z[0] + vv[0], Z[1] + vv[1]),
                             fmaxf(Z[2] + vv[2], Z[3] + vv[3]));
            m0 = fmaxf(m0, __shfl_xor(m0, 1, 64));
            m0 = fmaxf(m0, __shfl_xor(m0, 2, 64));
            float s0 = __expf(Z[0] + vv[0] - m0) + __expf(Z[1] + vv[1] - m0) +
                       __expf(Z[2] + vv[2] - m0) + __expf(Z[3] + vv[3] - m0);
            s0 += __shfl_xor(s0, 1, 64);
            s0 += __shfl_xor(s0, 2, 64);
            u = lm - (m0 + __logf(s0));
            float cm[4], cs[4];
#pragma unroll
            for (int j = 0; j < 4; j++) cm[j] = Z[j] + u;
#pragma unroll
            for (int msk = 4; msk < 64; msk <<= 1)
#pragma unroll
                for (int j = 0; j < 4; j++)
                    cm[j] = fmaxf(cm[j], __shfl_xor(cm[j], msk, 64));
#pragma unroll
            for (int j = 0; j < 4; j++) cs[j] = __expf(Z[j] + u - cm[j]);
#pragma unroll
            for (int msk = 4; msk < 64; msk <<= 1)
#pragma unroll
                for (int j = 0; j < 4; j++) cs[j] += __shfl_xor(cs[j], msk, 64);
#pragma unroll
            for (int j = 0; j < 4; j++) vv[j] = lm - (cm[j] + __logf(cs[j]));
        }
#pragma unroll
        for (int j = 0; j < 4; j++)
            Zl[r * 17 + c0 + j] = __expf(Z[j] + u + vv[j]) * 16.0f;
        if (lane == 0) {
            // ---- H_pre / H_post softmax (extras already x scale)
            const float apre = alpha_pre_p[0], apost = alpha_post_p[0];
            float pv[4], qv[4], pm = -3e38f, qm = -3e38f;
#pragma unroll
            for (int s = 0; s < 4; s++) {
                pv[s] = apre  * extra[s]     + H_pre_logits[s];
                qv[s] = apost * extra[4 + s] + H_post_logits[s];
                pm = fmaxf(pm, pv[s]); qm = fmaxf(qm, qv[s]);
            }
            float ps = 0.f, qs = 0.f;
#pragma unroll
            for (int s = 0; s < 4; s++) {
                pv[s] = __expf(pv[s] - pm); qv[s] = __expf(qv[s] - qm);
                ps += pv[s]; qs += qv[s];
            }
#pragma unroll
            for (int s = 0; s < 4; s++) { hpre[s] = pv[s] / ps; hpost[s] = qv[s] / qs; }
        }
    }
    __syncthreads();                                          // (3)

    // ---- mixing: thread (q=wid, lane) computes out[so][q*256 + lane*4 .. +3]
    float4 busr[16];
#pragma unroll
    for (int s = 0; s < 16; s++)
        busr[s] = *(const float4*)&busf[s * 256 + lane * 4];
    float4 bo = *(const float4*)(branch_output + ((size_t)b * 2048 + lt) * 1024 + off);
#pragma unroll
    for (int so = 0; so < 4; so++) {
        float hp = hpost[so];
        float4 a;
        a.x = hp * bo.x; a.y = hp * bo.y; a.z = hp * bo.z; a.w = hp * bo.w;
#pragma unroll
        for (int s = 0; s < 16; s++) {
            float sv = Zl[s * 17 + so * 4 + wid];   // S[s][so*4+q], LDS broadcast
            float4 bu = busr[s];
            a.x += sv * bu.x; a.y += sv * bu.y; a.z += sv * bu.z; a.w += sv * bu.w;
        }
        *(float4*)(out + ((size_t)(b * 4 + so) * 2048 + lt) * 1024 + off) = a;
    }

    // ---- branch_input: sum_s hpre[s] * bus[s][off]  (chunks s*4+wid)
    float4 bi = {0.f, 0.f, 0.f, 0.f};
#pragma unroll
    for (int s = 0; s < 4; s++) {
        float4 v = busr[s * 4 + wid];
        float h = hpre[s];
        bi.x += h * v.x; bi.y += h * v.y; bi.z += h * v.z; bi.w += h * v.w;
    }
    *(float4*)(out + OUT0 + ((size_t)b * 2048 + lt) * 1024 + off) = bi;
}

// ---------------------------------------------------------------------------
extern "C" void kernel_launch(void* const* d_in, const int* in_sizes, int n_in,
                              void* d_out, int out_size, void* d_ws, size_t ws_size,
                              hipStream_t stream) {
    const float* residuals  = (const float*)d_in[0];
    const float* branch_out = (const float*)d_in[1];
    const float* gamma      = (const float*)d_in[2];
    const float* H_res_log  = (const float*)d_in[3];
    const float* phi_res    = (const float*)d_in[4];
    const float* alpha_res  = (const float*)d_in[5];
    const float* H_pre_log  = (const float*)d_in[6];
    const float* phi_pre    = (const float*)d_in[7];
    const float* alpha_pre  = (const float*)d_in[8];
    const float* H_post_log = (const float*)d_in[9];
    const float* phi_post   = (const float*)d_in[10];
    const float* alpha_post = (const float*)d_in[11];

    unsigned short* Wt = (unsigned short*)d_ws;                          // 320*4096 bf16
    float* raw_part = (float*)((char*)d_ws + (size_t)NPADW * BUSW * 2);  // 4*8192*288 f32
    float* out = (float*)d_out;

    hipLaunchKernelGGL(prep_w_kernel, dim3(NPADW * BUSW / 8 / 256), dim3(256), 0, stream,
                       gamma, phi_res, phi_pre, phi_post, Wt);
    hipLaunchKernelGGL(gemm_raw_kernel, dim3(NTOK / BM, KSPLIT), dim3(256), 0, stream,
                       residuals, Wt, raw_part);
    hipLaunchKernelGGL(fused_tail_kernel, dim3(NTOK), dim3(256), 0, stream,
                       residuals, branch_out, H_res_log, alpha_res,
                       H_pre_log, alpha_pre, H_post_log, alpha_post, raw_part, out);
}